// Round 1
// baseline (515.839 us; speedup 1.0000x reference)
//
#include <hip/hip_runtime.h>
#include <math.h>

#define NB 2
#define CIN 96
#define D2 192
#define D4 768
#define LL 9216
#define NN 16
#define DRR 6
#define NCHX 38   /* DR + 2N */
#define NCHUNK 96
#define CLEN 96

// ---- workspace layout (float offsets) ----
#define SZ_DELTA (2u*9216u*768u)        // 14,155,776
#define SZ_Y4    (2u*4u*9216u*192u)     // 14,155,776
#define SZ_BL    (2u*9216u*192u)        //  3,538,944
#define SZ_XDBL  (2u*9216u*38u)         //    700,416
#define SZ_SUM   (2u*4u*96u*192u*16u)   //  2,359,296
#define F_DELTA  0u
#define F_Y4     (F_DELTA + SZ_DELTA)
#define F_XX     F_Y4                    /* alias: dead before y4 written */
#define F_XC     (F_Y4 + SZ_BL)          /* alias: dead before y4 written */
#define F_ZS     (F_Y4 + SZ_Y4)
#define F_XT     (F_ZS + SZ_BL)
#define F_XDBL   (F_XT + SZ_BL)
#define F_PBUF   (F_XDBL + SZ_XDBL)
#define F_HBUF   (F_PBUF + SZ_SUM)

__device__ __forceinline__ float silu_f(float z) {
    return z / (1.0f + __expf(-z));
}

// K1: xz = x @ W_in + b_in; split -> xx (b,192,L) for conv, silu(z) -> zs (b,L,192)
__global__ __launch_bounds__(256) void k1_inproj(
    const float* __restrict__ x, const float* __restrict__ Win,
    const float* __restrict__ bin, float* __restrict__ xx, float* __restrict__ zs)
{
    __shared__ float xs[96][32];
    __shared__ float wsm[96][128];
    int tid = threadIdx.x;
    int gl0 = blockIdx.x * 32;
    int b = gl0 / LL;
    int l0 = gl0 % LL;

    for (int i = tid; i < 96 * 32; i += 256) {
        int c = i >> 5, li = i & 31;
        xs[c][li] = x[(size_t)(b * 96 + c) * LL + l0 + li];
    }
    int lg = (tid & 7) * 4;
    int eg = (tid >> 3) * 4;
    for (int ech = 0; ech < 384; ech += 128) {
        __syncthreads();
        for (int i = tid; i < 96 * 128; i += 256) {
            int c = i >> 7, e = i & 127;
            wsm[c][e] = Win[c * 384 + ech + e];
        }
        __syncthreads();
        float acc[4][4];
#pragma unroll
        for (int i = 0; i < 4; i++)
#pragma unroll
            for (int j = 0; j < 4; j++) acc[i][j] = 0.f;
        for (int c = 0; c < 96; c++) {
            float4 xv = *(const float4*)&xs[c][lg];
            float4 wv = *(const float4*)&wsm[c][eg];
            float xa[4] = {xv.x, xv.y, xv.z, xv.w};
            float wa[4] = {wv.x, wv.y, wv.z, wv.w};
#pragma unroll
            for (int i = 0; i < 4; i++)
#pragma unroll
                for (int j = 0; j < 4; j++) acc[i][j] += xa[i] * wa[j];
        }
        int ebase = ech + eg;
        if (ebase < 192) {
#pragma unroll
            for (int j = 0; j < 4; j++) {
                int e = ebase + j;
                float bb = bin[e];
                float4 v = {acc[0][j] + bb, acc[1][j] + bb, acc[2][j] + bb, acc[3][j] + bb};
                *(float4*)&xx[(size_t)(b * 192 + e) * LL + l0 + lg] = v;
            }
        } else {
#pragma unroll
            for (int i = 0; i < 4; i++) {
                int l = l0 + lg + i;
                float4 v;
                v.x = silu_f(acc[i][0] + bin[ebase + 0]);
                v.y = silu_f(acc[i][1] + bin[ebase + 1]);
                v.z = silu_f(acc[i][2] + bin[ebase + 2]);
                v.w = silu_f(acc[i][3] + bin[ebase + 3]);
                *(float4*)&zs[((size_t)b * LL + l) * 192 + (ebase - 192)] = v;
            }
        }
    }
}

// K2: depthwise 3x3 SAME conv + bias + silu : xx (b,192,96,96) -> xc (b,192,L)
__global__ __launch_bounds__(256) void k2_dwconv(
    const float* __restrict__ xx, const float* __restrict__ wdw,
    const float* __restrict__ bdw, float* __restrict__ xc)
{
    int gid = blockIdx.x * 256 + threadIdx.x;  // exactly 2*192*9216
    int l = gid % LL;
    int t = gid / LL;
    int d = t % D2;
    int h = l / 96, w = l % 96;
    float acc = bdw[d];
    const float* base = xx + (size_t)t * LL;
#pragma unroll
    for (int kh = 0; kh < 3; kh++) {
        int hh = h + kh - 1;
        if (hh < 0 || hh >= 96) continue;
#pragma unroll
        for (int kw = 0; kw < 3; kw++) {
            int ww2 = w + kw - 1;
            if (ww2 < 0 || ww2 >= 96) continue;
            acc += base[hh * 96 + ww2] * wdw[d * 9 + kh * 3 + kw];
        }
    }
    xc[gid] = silu_f(acc);
}

// K2b: transpose xc (b,192,L) -> xt (b,L,192)
__global__ __launch_bounds__(256) void k2b_transpose(
    const float* __restrict__ xc, float* __restrict__ xt)
{
    __shared__ float tile[32][33];
    int bid = blockIdx.x;
    int lt = bid % 288;
    int r = bid / 288;
    int dti = r % 6;
    int b = r / 6;
    int l0 = lt * 32, d0 = dti * 32;
    int tx = threadIdx.x & 31, ty = threadIdx.x >> 5;  // 32 x 8
#pragma unroll
    for (int k = 0; k < 4; k++) {
        int row = ty + k * 8;
        tile[row][tx] = xc[(size_t)(b * D2 + d0 + row) * LL + l0 + tx];
    }
    __syncthreads();
#pragma unroll
    for (int k = 0; k < 4; k++) {
        int row = ty + k * 8;  // l offset
        xt[((size_t)b * LL + l0 + row) * D2 + d0 + tx] = tile[tx][row];
    }
}

// K3: xdbl[b,l,j] (+)= sum_d xt[b, l or flip(l), d] * (Wx[d+woff,j]+Wx[d+woff+192,j])
__global__ __launch_bounds__(256) void k3_xdbl(
    const float* __restrict__ xt, const float* __restrict__ Wx,
    float* __restrict__ xdbl, int woff, int flip, int accum)
{
    __shared__ float wf[192][38];
    __shared__ float xf[16][192];
    int tid = threadIdx.x;
    int bid = blockIdx.x;
    int b = bid / 576;
    int l0 = (bid % 576) * 16;
    for (int i = tid; i < 192 * 38; i += 256) {
        int d = i / 38, j = i % 38;
        wf[d][j] = Wx[(d + woff) * 38 + j] + Wx[(d + woff + 192) * 38 + j];
    }
    for (int i = tid; i < 16 * 192; i += 256) {
        int li = i / 192, d = i % 192;
        int l = flip ? (LL - 1 - (l0 + li)) : (l0 + li);
        xf[li][d] = xt[((size_t)b * LL + l) * 192 + d];
    }
    __syncthreads();
    for (int o = tid; o < 16 * 38; o += 256) {
        int li = o / 38, j = o % 38;
        float acc = 0.f;
        for (int d = 0; d < 192; d++) acc += xf[li][d] * wf[d][j];
        size_t idx = ((size_t)b * LL + l0 + li) * 38 + j;
        if (accum) xdbl[idx] += acc; else xdbl[idx] = acc;
    }
}

// K3b: delta[b,l,d] = softplus(dt_r @ W_delta + b_delta), layout (b*L, 768)
__global__ __launch_bounds__(256) void k3b_delta(
    const float* __restrict__ xdbl, const float* __restrict__ Wd,
    const float* __restrict__ bdl, float* __restrict__ delta)
{
    int gl = blockIdx.x;  // 18432
    int tid = threadIdx.x;
    float dtr[6];
#pragma unroll
    for (int r = 0; r < 6; r++) dtr[r] = xdbl[(size_t)gl * 38 + r];
    for (int d = tid; d < 768; d += 256) {
        float acc = bdl[d];
#pragma unroll
        for (int r = 0; r < 6; r++) acc += dtr[r] * Wd[r * 768 + d];
        float sp = (acc > 20.f) ? acc : log1pf(__expf(acc));
        delta[(size_t)gl * 768 + d] = sp;
    }
}

// K4 pass1: per-chunk local scan, emit P = prod(dA), hloc (from h=0)
__global__ __launch_bounds__(192) void k4_pass1(
    const float* __restrict__ delta, const float* __restrict__ xt,
    const float* __restrict__ xdbl, const float* __restrict__ Alog,
    float* __restrict__ Pbuf, float* __restrict__ Hbuf)
{
    __shared__ float Bt[96][16];
    int tid = threadIdx.x;
    int bid = blockIdx.x;
    int chunk = bid % 96;
    int bd = bid / 96;        // b*4 + dir
    int b = bd >> 2, dir = bd & 3;
    int l0 = chunk * 96;
    for (int i = tid; i < 96 * 16; i += 192) {
        int t = i >> 4, n = i & 15;
        Bt[t][n] = xdbl[((size_t)b * LL + l0 + t) * 38 + 6 + n];
    }
    __syncthreads();
    int c = tid;
    int d4 = dir * 192 + c;
    float a[16], h[16], P[16];
#pragma unroll
    for (int n = 0; n < 16; n++) {
        a[n] = -__expf(Alog[d4 * 16 + n]);
        h[n] = 0.f; P[n] = 1.f;
    }
    const float* dptr = delta + ((size_t)b * LL + l0) * 768 + d4;
    for (int t = 0; t < 96; t++) {
        float dt = dptr[(size_t)t * 768];
        int lp = (dir < 2) ? (l0 + t) : (LL - 1 - (l0 + t));
        float u = xt[((size_t)b * LL + lp) * 192 + c];
        float dtu = dt * u;
        float Bv[16];
        *(float4*)&Bv[0]  = *(const float4*)&Bt[t][0];
        *(float4*)&Bv[4]  = *(const float4*)&Bt[t][4];
        *(float4*)&Bv[8]  = *(const float4*)&Bt[t][8];
        *(float4*)&Bv[12] = *(const float4*)&Bt[t][12];
#pragma unroll
        for (int n = 0; n < 16; n++) {
            float e = __expf(dt * a[n]);
            h[n] = e * h[n] + dtu * Bv[n];
            P[n] *= e;
        }
    }
    size_t base = (((size_t)bd * 96 + chunk) * 192 + c) * 16;
#pragma unroll
    for (int n = 0; n < 16; n++) { Pbuf[base + n] = P[n]; Hbuf[base + n] = h[n]; }
}

// K4 pass2: scan over chunk summaries; rewrite Hbuf[k] := h_start for chunk k
__global__ __launch_bounds__(256) void k4_pass2(
    const float* __restrict__ Pbuf, float* __restrict__ Hbuf)
{
    int lane = blockIdx.x * 256 + threadIdx.x;  // 24576
    int bd = lane / 3072;
    int cn = lane % 3072;
    float h = 0.f;
#pragma unroll 8
    for (int k = 0; k < 96; k++) {
        size_t idx = ((size_t)bd * 96 + k) * 3072 + cn;
        float Pv = Pbuf[idx];
        float hl = Hbuf[idx];
        Hbuf[idx] = h;
        h = Pv * h + hl;
    }
}

// K4 pass3: replay chunk from h_start, emit y into (b,dir,Lphys,192)
__global__ __launch_bounds__(192) void k4_pass3(
    const float* __restrict__ delta, const float* __restrict__ xt,
    const float* __restrict__ xdbl, const float* __restrict__ Alog,
    const float* __restrict__ Dp, const float* __restrict__ Hbuf,
    float* __restrict__ y4)
{
    __shared__ float Bt[96][16];
    __shared__ float Ct[96][16];
    int tid = threadIdx.x;
    int bid = blockIdx.x;
    int chunk = bid % 96;
    int bd = bid / 96;
    int b = bd >> 2, dir = bd & 3;
    int l0 = chunk * 96;
    for (int i = tid; i < 96 * 16; i += 192) {
        int t = i >> 4, n = i & 15;
        size_t rb = ((size_t)b * LL + l0 + t) * 38;
        Bt[t][n] = xdbl[rb + 6 + n];
        Ct[t][n] = xdbl[rb + 22 + n];
    }
    __syncthreads();
    int c = tid;
    int d4 = dir * 192 + c;
    float a[16], h[16];
    size_t base = (((size_t)bd * 96 + chunk) * 192 + c) * 16;
#pragma unroll
    for (int n = 0; n < 16; n++) {
        a[n] = -__expf(Alog[d4 * 16 + n]);
        h[n] = Hbuf[base + n];
    }
    float Dv = Dp[d4];
    const float* dptr = delta + ((size_t)b * LL + l0) * 768 + d4;
    for (int t = 0; t < 96; t++) {
        float dt = dptr[(size_t)t * 768];
        int lp = (dir < 2) ? (l0 + t) : (LL - 1 - (l0 + t));
        float u = xt[((size_t)b * LL + lp) * 192 + c];
        float dtu = dt * u;
        float Bv[16], Cv[16];
        *(float4*)&Bv[0]  = *(const float4*)&Bt[t][0];
        *(float4*)&Bv[4]  = *(const float4*)&Bt[t][4];
        *(float4*)&Bv[8]  = *(const float4*)&Bt[t][8];
        *(float4*)&Bv[12] = *(const float4*)&Bt[t][12];
        *(float4*)&Cv[0]  = *(const float4*)&Ct[t][0];
        *(float4*)&Cv[4]  = *(const float4*)&Ct[t][4];
        *(float4*)&Cv[8]  = *(const float4*)&Ct[t][8];
        *(float4*)&Cv[12] = *(const float4*)&Ct[t][12];
        float yv = Dv * u;
#pragma unroll
        for (int n = 0; n < 16; n++) {
            float e = __expf(dt * a[n]);
            h[n] = e * h[n] + dtu * Bv[n];
            yv += h[n] * Cv[n];
        }
        y4[((size_t)bd * LL + lp) * 192 + c] = yv;
    }
}

// K5: yh = sum of 4 dirs; LayerNorm(192); * silu(z); @ W_out -> out (b,96,H,W)
__global__ __launch_bounds__(256) void k5_out(
    const float* __restrict__ y4, const float* __restrict__ zs,
    const float* __restrict__ lng, const float* __restrict__ lnb,
    const float* __restrict__ Wout, float* __restrict__ out)
{
    __shared__ float acts[16][192];
    __shared__ float wsh[96][96];
    int tid = threadIdx.x;
    int wv = tid >> 6;
    int lane = tid & 63;
    int gl0 = blockIdx.x * 16;
    int b = gl0 / LL;
    int l0 = gl0 % LL;

    for (int rep = 0; rep < 4; rep++) {
        int li = wv * 4 + rep;
        int l = l0 + li;
        float yv[3], zv[3];
        float s1 = 0.f, s2 = 0.f;
#pragma unroll
        for (int k = 0; k < 3; k++) {
            int c = lane + k * 64;
            size_t off = ((size_t)(b * 4) * LL + l) * 192 + c;
            const size_t ds = (size_t)LL * 192;
            float y = y4[off] + y4[off + ds] + y4[off + 2 * ds] + y4[off + 3 * ds];
            yv[k] = y;
            zv[k] = zs[((size_t)b * LL + l) * 192 + c];
            s1 += y; s2 += y * y;
        }
#pragma unroll
        for (int o = 32; o; o >>= 1) {
            s1 += __shfl_xor(s1, o, 64);
            s2 += __shfl_xor(s2, o, 64);
        }
        float mean = s1 * (1.f / 192.f);
        float var = s2 * (1.f / 192.f) - mean * mean;
        float rs = rsqrtf(var + 1e-5f);
#pragma unroll
        for (int k = 0; k < 3; k++) {
            int c = lane + k * 64;
            float yn = (yv[k] - mean) * rs * lng[c] + lnb[c];
            acts[li][c] = yn * zv[k];
        }
    }
    float o0[4] = {0.f, 0.f, 0.f, 0.f};
    float o1[4] = {0.f, 0.f, 0.f, 0.f};
    for (int half = 0; half < 2; half++) {
        __syncthreads();
        for (int i = tid; i < 96 * 96; i += 256)
            wsh[i / 96][i % 96] = Wout[(half * 96 + i / 96) * 96 + i % 96];
        __syncthreads();
        for (int rep = 0; rep < 4; rep++) {
            int li = wv * 4 + rep;
            for (int c = 0; c < 96; c++) {
                float av = acts[li][half * 96 + c];
                o0[rep] += av * wsh[c][lane];
                if (lane < 32) o1[rep] += av * wsh[c][64 + lane];
            }
        }
    }
    int l0w = l0 + wv * 4;
    {
        float4 v = {o0[0], o0[1], o0[2], o0[3]};
        *(float4*)&out[((size_t)(b * 96) + lane) * LL + l0w] = v;
    }
    if (lane < 32) {
        float4 v = {o1[0], o1[1], o1[2], o1[3]};
        *(float4*)&out[((size_t)(b * 96) + 64 + lane) * LL + l0w] = v;
    }
}

extern "C" void kernel_launch(void* const* d_in, const int* in_sizes, int n_in,
                              void* d_out, int out_size, void* d_ws, size_t ws_size,
                              hipStream_t stream)
{
    const float* x    = (const float*)d_in[0];
    const float* Win  = (const float*)d_in[1];
    const float* bin  = (const float*)d_in[2];
    const float* wdw  = (const float*)d_in[3];
    const float* bdw  = (const float*)d_in[4];
    const float* Alog = (const float*)d_in[5];
    const float* Dp   = (const float*)d_in[6];
    const float* Wx   = (const float*)d_in[7];
    const float* Wd   = (const float*)d_in[8];
    const float* bdl  = (const float*)d_in[9];
    const float* lng  = (const float*)d_in[10];
    const float* lnb  = (const float*)d_in[11];
    const float* Wout = (const float*)d_in[12];
    float* out = (float*)d_out;

    float* ws    = (float*)d_ws;
    float* delta = ws + F_DELTA;
    float* y4    = ws + F_Y4;
    float* xx    = ws + F_XX;    // aliases y4[0 : 3.5M)  (dead before y4 write)
    float* xc    = ws + F_XC;    // aliases y4[3.5M : 7M)
    float* zs    = ws + F_ZS;
    float* xt    = ws + F_XT;
    float* xdbl  = ws + F_XDBL;
    float* Pbuf  = ws + F_PBUF;
    float* Hbuf  = ws + F_HBUF;

    k1_inproj<<<576, 256, 0, stream>>>(x, Win, bin, xx, zs);
    k2_dwconv<<<13824, 256, 0, stream>>>(xx, wdw, bdw, xc);
    k2b_transpose<<<3456, 256, 0, stream>>>(xc, xt);
    k3_xdbl<<<1152, 256, 0, stream>>>(xt, Wx, xdbl, 0, 0, 0);
    k3_xdbl<<<1152, 256, 0, stream>>>(xt, Wx, xdbl, 384, 1, 1);
    k3b_delta<<<18432, 256, 0, stream>>>(xdbl, Wd, bdl, delta);
    k4_pass1<<<768, 192, 0, stream>>>(delta, xt, xdbl, Alog, Pbuf, Hbuf);
    k4_pass2<<<96, 256, 0, stream>>>(Pbuf, Hbuf);
    k4_pass3<<<768, 192, 0, stream>>>(delta, xt, xdbl, Alog, Dp, Hbuf, y4);
    k5_out<<<1152, 256, 0, stream>>>(y4, zs, lng, lnb, Wout, out);
}

// Round 2
// 385.735 us; speedup vs baseline: 1.3373x; 1.3373x over previous
//
#include <hip/hip_runtime.h>
#include <math.h>

#define CIN 96
#define D2 192
#define D4 768
#define LL 9216
#define NN 16

// ---- workspace layout (float offsets) ----
#define SZ_Y4    (2u*4u*9216u*192u)     // 14,155,776
#define SZ_BL    (2u*9216u*192u)        //  3,538,944
#define SZ_XDBL  (2u*9216u*38u)         //    700,416
#define SZ_SUM   (2u*4u*96u*192u*16u)   //  2,359,296
#define F_Y4     0u
#define F_XX     0u                      /* alias: xx dead before y4 written */
#define F_ZS     (F_Y4 + SZ_Y4)
#define F_XT     (F_ZS + SZ_BL)
#define F_XDBL   (F_XT + SZ_BL)
#define F_PBUF   (F_XDBL + SZ_XDBL)
#define F_HBUF   (F_PBUF + SZ_SUM)

__device__ __forceinline__ float silu_f(float z) {
    return z / (1.0f + __expf(-z));
}

// K1: xz = x @ W_in + b_in; first half -> xx (b,192,L), silu(second half) -> zs (b,L,192)
// block: 64 l, 256 threads (16 lg x 16 eg), per-thread 4l x 4e, 6 e-chunks of 64
__global__ __launch_bounds__(256) void k1_inproj(
    const float* __restrict__ x, const float* __restrict__ Win,
    const float* __restrict__ bin, float* __restrict__ xx, float* __restrict__ zs)
{
    __shared__ float xs[96][68];
    __shared__ float wsm[96][68];
    int tid = threadIdx.x;
    int gl0 = blockIdx.x * 64;
    int b = gl0 / LL;
    int l0 = gl0 % LL;

    for (int i = tid; i < 96 * 64; i += 256) {
        int k = i >> 6, li = i & 63;
        xs[k][li] = x[(size_t)(b * 96 + k) * LL + l0 + li];
    }
    int lg = tid >> 4;   // 0..15 -> l = l0 + lg*4 ..
    int eg = tid & 15;   // e in chunk = eg*4 ..
    for (int ech = 0; ech < 384; ech += 64) {
        __syncthreads();
        for (int i = tid; i < 96 * 64; i += 256) {
            int k = i >> 6, e = i & 63;
            wsm[k][e] = Win[k * 384 + ech + e];
        }
        __syncthreads();
        float acc[4][4];
#pragma unroll
        for (int i = 0; i < 4; i++)
#pragma unroll
            for (int j = 0; j < 4; j++) acc[i][j] = 0.f;
        for (int k = 0; k < 96; k++) {
            float4 xv = *(const float4*)&xs[k][lg * 4];
            float4 wv = *(const float4*)&wsm[k][eg * 4];
            float xa[4] = {xv.x, xv.y, xv.z, xv.w};
            float wa[4] = {wv.x, wv.y, wv.z, wv.w};
#pragma unroll
            for (int i = 0; i < 4; i++)
#pragma unroll
                for (int j = 0; j < 4; j++) acc[i][j] += xa[i] * wa[j];
        }
        int e0 = ech + eg * 4;
        if (e0 < 192) {
#pragma unroll
            for (int j = 0; j < 4; j++) {
                int e = e0 + j;
                float bb = bin[e];
                float4 v = {acc[0][j] + bb, acc[1][j] + bb, acc[2][j] + bb, acc[3][j] + bb};
                *(float4*)&xx[(size_t)(b * 192 + e) * LL + l0 + lg * 4] = v;
            }
        } else {
#pragma unroll
            for (int i = 0; i < 4; i++) {
                int l = l0 + lg * 4 + i;
                float4 v;
                v.x = silu_f(acc[i][0] + bin[e0 + 0]);
                v.y = silu_f(acc[i][1] + bin[e0 + 1]);
                v.z = silu_f(acc[i][2] + bin[e0 + 2]);
                v.w = silu_f(acc[i][3] + bin[e0 + 3]);
                *(float4*)&zs[((size_t)b * LL + l) * 192 + (e0 - 192)] = v;
            }
        }
    }
}

// K2: depthwise 3x3 conv + bias + silu, fused transpose: xx (b,192,96,96) -> xt (b,L,192)
// block = (b, dgroup of 32, h). 192 threads: (dhalf 2) x (w 96).
__global__ __launch_bounds__(192) void k2_conv(
    const float* __restrict__ xx, const float* __restrict__ wdw,
    const float* __restrict__ bdw, float* __restrict__ xt)
{
    __shared__ float tile[32][97];
    __shared__ float wsm[32][9];
    __shared__ float bs[32];
    int tid = threadIdx.x;
    int bid = blockIdx.x;
    int h = bid % 96;
    int r = bid / 96;
    int dg = r % 6;
    int b = r / 6;

    for (int i = tid; i < 288; i += 192) wsm[i / 9][i % 9] = wdw[(dg * 32 + i / 9) * 9 + (i % 9)];
    if (tid < 32) bs[tid] = bdw[dg * 32 + tid];
    __syncthreads();

    int w = tid % 96;
    int dhalf = tid / 96;
    for (int p = 0; p < 16; p++) {
        int dsub = 2 * p + dhalf;
        const float* base = xx + (size_t)(b * 192 + dg * 32 + dsub) * LL;
        float acc = bs[dsub];
#pragma unroll
        for (int kh = 0; kh < 3; kh++) {
            int hh = h + kh - 1;
            if (hh < 0 || hh >= 96) continue;
            const float* row = base + hh * 96;
#pragma unroll
            for (int kw = 0; kw < 3; kw++) {
                int ww = w + kw - 1;
                if (ww < 0 || ww >= 96) continue;
                acc += row[ww] * wsm[dsub][kh * 3 + kw];
            }
        }
        tile[dsub][w] = silu_f(acc);
    }
    __syncthreads();
    for (int i = tid; i < 768; i += 192) {
        int q = i & 7, ls = i >> 3;
        float4 v = {tile[q * 4 + 0][ls], tile[q * 4 + 1][ls], tile[q * 4 + 2][ls], tile[q * 4 + 3][ls]};
        *(float4*)&xt[((size_t)b * LL + h * 96 + ls) * 192 + dg * 32 + q * 4] = v;
    }
}

// K3: xdbl[b,l,:38] = xt[b,l,:] @ (Wx[0:192]+Wx[192:384]) + xt[b,flip(l),:] @ (Wx[384:576]+Wx[576:768])
// block: 48 l, 192 threads (24 lig x 8 jg), per-thread 2l x 6j, x from global (L1)
__global__ __launch_bounds__(192) void k3_xdbl(
    const float* __restrict__ xt, const float* __restrict__ Wx,
    float* __restrict__ xdbl)
{
    __shared__ float wf0[192][40];
    __shared__ float wf1[192][40];
    int tid = threadIdx.x;
    int bid = blockIdx.x;
    int b = bid / 192;
    int l0 = (bid % 192) * 48;

    for (int i = tid; i < 192 * 40; i += 192) {
        int d = i / 40, j = i % 40;
        float v0 = 0.f, v1 = 0.f;
        if (j < 38) {
            v0 = Wx[d * 38 + j] + Wx[(d + 192) * 38 + j];
            v1 = Wx[(d + 384) * 38 + j] + Wx[(d + 576) * 38 + j];
        }
        wf0[d][j] = v0;
        wf1[d][j] = v1;
    }
    __syncthreads();
    int lig = tid / 8, jg = tid % 8;
    int li0 = l0 + lig * 2;
    int j0 = jg * 6;
    const float* xf0 = xt + ((size_t)b * LL + li0) * 192;
    const float* xf1 = xf0 + 192;
    const float* xr0 = xt + ((size_t)b * LL + (LL - 1 - li0)) * 192;
    const float* xr1 = xr0 - 192;
    float acc0[6], acc1[6];
#pragma unroll
    for (int j = 0; j < 6; j++) { acc0[j] = 0.f; acc1[j] = 0.f; }
    for (int d = 0; d < 192; d++) {
        float x0 = xf0[d], x1 = xf1[d];
        float r0 = xr0[d], r1 = xr1[d];
        float w0[6], w1[6];
        *(float2*)&w0[0] = *(const float2*)&wf0[d][j0];
        *(float2*)&w0[2] = *(const float2*)&wf0[d][j0 + 2];
        *(float2*)&w0[4] = *(const float2*)&wf0[d][j0 + 4];
        *(float2*)&w1[0] = *(const float2*)&wf1[d][j0];
        *(float2*)&w1[2] = *(const float2*)&wf1[d][j0 + 2];
        *(float2*)&w1[4] = *(const float2*)&wf1[d][j0 + 4];
#pragma unroll
        for (int j = 0; j < 6; j++) {
            acc0[j] += x0 * w0[j] + r0 * w1[j];
            acc1[j] += x1 * w0[j] + r1 * w1[j];
        }
    }
#pragma unroll
    for (int j = 0; j < 6; j++) {
        int jj = j0 + j;
        if (jj < 38) {
            xdbl[((size_t)b * LL + li0) * 38 + jj] = acc0[j];
            xdbl[((size_t)b * LL + li0 + 1) * 38 + jj] = acc1[j];
        }
    }
}

// K4 pass1: per-chunk local scan (h from 0) with fused delta; emit S-based P and hloc
__global__ __launch_bounds__(192) void k4_pass1(
    const float* __restrict__ xt, const float* __restrict__ xdbl,
    const float* __restrict__ Wd, const float* __restrict__ bdl,
    const float* __restrict__ Alog,
    float* __restrict__ Pbuf, float* __restrict__ Hbuf)
{
    __shared__ float Bt[96][16];
    __shared__ float Dt[96][6];
    int tid = threadIdx.x;
    int bid = blockIdx.x;
    int chunk = bid % 96;
    int bd = bid / 96;
    int b = bd >> 2, dir = bd & 3;
    int l0 = chunk * 96;
    for (int i = tid; i < 96 * 16; i += 192) {
        int t = i >> 4, n = i & 15;
        Bt[t][n] = xdbl[((size_t)b * LL + l0 + t) * 38 + 6 + n];
    }
    for (int i = tid; i < 96 * 6; i += 192) {
        int t = i / 6, rr = i - 6 * t;
        Dt[t][rr] = xdbl[((size_t)b * LL + l0 + t) * 38 + rr];
    }
    __syncthreads();
    int c = tid;
    int d4 = dir * 192 + c;
    float a[16];
#pragma unroll
    for (int n = 0; n < 16; n++) a[n] = -__expf(Alog[d4 * 16 + n]);
    float a0 = a[0];
    bool fast = true;
#pragma unroll
    for (int n = 0; n < 16; n++) {
        float tgt = (n + 1) * a0;
        fast = fast && (fabsf(a[n] - tgt) <= 1e-5f * fabsf(tgt));
    }
    float wd[6];
#pragma unroll
    for (int rr = 0; rr < 6; rr++) wd[rr] = Wd[rr * 768 + d4];
    float bde = bdl[d4];
    float h[16];
#pragma unroll
    for (int n = 0; n < 16; n++) h[n] = 0.f;
    float S = 0.f;
    const float* xtp = xt + (size_t)b * LL * 192;
    for (int t = 0; t < 96; t++) {
        float s = bde;
#pragma unroll
        for (int rr = 0; rr < 6; rr++) s += Dt[t][rr] * wd[rr];
        float dt = (s > 20.f) ? s : __logf(1.f + __expf(s));
        S += dt;
        int lp = (dir < 2) ? (l0 + t) : (LL - 1 - (l0 + t));
        float u = xtp[(size_t)lp * 192 + c];
        float dtu = dt * u;
        float Bv[16];
        *(float4*)&Bv[0]  = *(const float4*)&Bt[t][0];
        *(float4*)&Bv[4]  = *(const float4*)&Bt[t][4];
        *(float4*)&Bv[8]  = *(const float4*)&Bt[t][8];
        *(float4*)&Bv[12] = *(const float4*)&Bt[t][12];
        if (fast) {
            float e1 = __expf(dt * a0);
            float ep = 1.f;
#pragma unroll
            for (int n = 0; n < 16; n++) {
                ep *= e1;
                h[n] = ep * h[n] + dtu * Bv[n];
            }
        } else {
#pragma unroll
            for (int n = 0; n < 16; n++) {
                float e = __expf(dt * a[n]);
                h[n] = e * h[n] + dtu * Bv[n];
            }
        }
    }
    size_t base = (((size_t)bd * 96 + chunk) * 192 + c) * 16;
#pragma unroll
    for (int n = 0; n < 16; n++) {
        Pbuf[base + n] = __expf(a[n] * S);   // == prod_t exp(dt*a[n])
        Hbuf[base + n] = h[n];
    }
}

// K4 pass2: scan over chunk summaries; rewrite Hbuf[k] := h_start for chunk k
__global__ __launch_bounds__(256) void k4_pass2(
    const float* __restrict__ Pbuf, float* __restrict__ Hbuf)
{
    int lane = blockIdx.x * 256 + threadIdx.x;  // 24576
    int bd = lane / 3072;
    int cn = lane % 3072;
    float h = 0.f;
#pragma unroll 8
    for (int k = 0; k < 96; k++) {
        size_t idx = ((size_t)bd * 96 + k) * 3072 + cn;
        float Pv = Pbuf[idx];
        float hl = Hbuf[idx];
        Hbuf[idx] = h;
        h = Pv * h + hl;
    }
}

// K4 pass3: replay chunk from h_start with fused delta, emit y into (b,dir,Lphys,192)
__global__ __launch_bounds__(192) void k4_pass3(
    const float* __restrict__ xt, const float* __restrict__ xdbl,
    const float* __restrict__ Wd, const float* __restrict__ bdl,
    const float* __restrict__ Alog, const float* __restrict__ Dp,
    const float* __restrict__ Hbuf, float* __restrict__ y4)
{
    __shared__ float Bt[96][16];
    __shared__ float Ct[96][16];
    __shared__ float Dt[96][6];
    int tid = threadIdx.x;
    int bid = blockIdx.x;
    int chunk = bid % 96;
    int bd = bid / 96;
    int b = bd >> 2, dir = bd & 3;
    int l0 = chunk * 96;
    for (int i = tid; i < 96 * 16; i += 192) {
        int t = i >> 4, n = i & 15;
        size_t rb = ((size_t)b * LL + l0 + t) * 38;
        Bt[t][n] = xdbl[rb + 6 + n];
        Ct[t][n] = xdbl[rb + 22 + n];
    }
    for (int i = tid; i < 96 * 6; i += 192) {
        int t = i / 6, rr = i - 6 * t;
        Dt[t][rr] = xdbl[((size_t)b * LL + l0 + t) * 38 + rr];
    }
    __syncthreads();
    int c = tid;
    int d4 = dir * 192 + c;
    float a[16], h[16];
    size_t base = (((size_t)bd * 96 + chunk) * 192 + c) * 16;
#pragma unroll
    for (int n = 0; n < 16; n++) {
        a[n] = -__expf(Alog[d4 * 16 + n]);
        h[n] = Hbuf[base + n];
    }
    float a0 = a[0];
    bool fast = true;
#pragma unroll
    for (int n = 0; n < 16; n++) {
        float tgt = (n + 1) * a0;
        fast = fast && (fabsf(a[n] - tgt) <= 1e-5f * fabsf(tgt));
    }
    float wd[6];
#pragma unroll
    for (int rr = 0; rr < 6; rr++) wd[rr] = Wd[rr * 768 + d4];
    float bde = bdl[d4];
    float Dv = Dp[d4];
    const float* xtp = xt + (size_t)b * LL * 192;
    for (int t = 0; t < 96; t++) {
        float s = bde;
#pragma unroll
        for (int rr = 0; rr < 6; rr++) s += Dt[t][rr] * wd[rr];
        float dt = (s > 20.f) ? s : __logf(1.f + __expf(s));
        int lp = (dir < 2) ? (l0 + t) : (LL - 1 - (l0 + t));
        float u = xtp[(size_t)lp * 192 + c];
        float dtu = dt * u;
        float Bv[16], Cv[16];
        *(float4*)&Bv[0]  = *(const float4*)&Bt[t][0];
        *(float4*)&Bv[4]  = *(const float4*)&Bt[t][4];
        *(float4*)&Bv[8]  = *(const float4*)&Bt[t][8];
        *(float4*)&Bv[12] = *(const float4*)&Bt[t][12];
        *(float4*)&Cv[0]  = *(const float4*)&Ct[t][0];
        *(float4*)&Cv[4]  = *(const float4*)&Ct[t][4];
        *(float4*)&Cv[8]  = *(const float4*)&Ct[t][8];
        *(float4*)&Cv[12] = *(const float4*)&Ct[t][12];
        float yv = Dv * u;
        if (fast) {
            float e1 = __expf(dt * a0);
            float ep = 1.f;
#pragma unroll
            for (int n = 0; n < 16; n++) {
                ep *= e1;
                h[n] = ep * h[n] + dtu * Bv[n];
                yv += h[n] * Cv[n];
            }
        } else {
#pragma unroll
            for (int n = 0; n < 16; n++) {
                float e = __expf(dt * a[n]);
                h[n] = e * h[n] + dtu * Bv[n];
                yv += h[n] * Cv[n];
            }
        }
        y4[((size_t)bd * LL + lp) * 192 + c] = yv;
    }
}

// K5: sum 4 dirs; LayerNorm(192); * silu(z) (pre-applied); @ W_out -> out (b,96,H,W)
// block: 64 l, 256 threads. LN by wave (16 rows/wave), then 4lx6n register-tiled GEMM.
__global__ __launch_bounds__(256) void k5_out(
    const float* __restrict__ y4, const float* __restrict__ zs,
    const float* __restrict__ lng, const float* __restrict__ lnb,
    const float* __restrict__ Wout, float* __restrict__ out)
{
    __shared__ float acts[64][194];
    __shared__ float wsh[32][100];
    int tid = threadIdx.x;
    int wv = tid >> 6;
    int lane = tid & 63;
    int gl0 = blockIdx.x * 64;
    int b = gl0 / LL;
    int l0 = gl0 % LL;
    const size_t ds = (size_t)LL * 192;

    for (int i = 0; i < 16; i++) {
        int rrow = wv * 16 + i;
        int l = l0 + rrow;
        float yv[3], zv[3];
        float s1 = 0.f, s2 = 0.f;
#pragma unroll
        for (int k = 0; k < 3; k++) {
            int c = lane + k * 64;
            size_t off = ((size_t)(b * 4) * LL + l) * 192 + c;
            float y = y4[off] + y4[off + ds] + y4[off + 2 * ds] + y4[off + 3 * ds];
            yv[k] = y;
            zv[k] = zs[((size_t)b * LL + l) * 192 + c];
            s1 += y; s2 += y * y;
        }
#pragma unroll
        for (int o = 32; o; o >>= 1) {
            s1 += __shfl_xor(s1, o, 64);
            s2 += __shfl_xor(s2, o, 64);
        }
        float mean = s1 * (1.f / 192.f);
        float var = s2 * (1.f / 192.f) - mean * mean;
        float rs = rsqrtf(var + 1e-5f);
#pragma unroll
        for (int k = 0; k < 3; k++) {
            int c = lane + k * 64;
            float yn = (yv[k] - mean) * rs * lng[c] + lnb[c];
            acts[rrow][c] = yn * zv[k];
        }
    }

    int ty = tid >> 4;   // 0..15 : rows ty*4..+3
    int tx = tid & 15;   // cols tx*6..+5
    float o[4][6];
#pragma unroll
    for (int i = 0; i < 4; i++)
#pragma unroll
        for (int j = 0; j < 6; j++) o[i][j] = 0.f;

    for (int kc = 0; kc < 192; kc += 32) {
        __syncthreads();
        for (int i = tid; i < 3072; i += 256)
            wsh[i / 96][i % 96] = Wout[(kc + i / 96) * 96 + i % 96];
        __syncthreads();
        for (int kk = 0; kk < 32; kk++) {
            float av[4];
#pragma unroll
            for (int i = 0; i < 4; i++) av[i] = acts[ty * 4 + i][kc + kk];
            float wvv[6];
#pragma unroll
            for (int j = 0; j < 6; j++) wvv[j] = wsh[kk][tx * 6 + j];
#pragma unroll
            for (int i = 0; i < 4; i++)
#pragma unroll
                for (int j = 0; j < 6; j++) o[i][j] += av[i] * wvv[j];
        }
    }
#pragma unroll
    for (int i = 0; i < 4; i++) {
        int l = l0 + ty * 4 + i;
#pragma unroll
        for (int j = 0; j < 6; j++) {
            int n = tx * 6 + j;
            out[((size_t)(b * 96) + n) * LL + l] = o[i][j];
        }
    }
}

extern "C" void kernel_launch(void* const* d_in, const int* in_sizes, int n_in,
                              void* d_out, int out_size, void* d_ws, size_t ws_size,
                              hipStream_t stream)
{
    const float* x    = (const float*)d_in[0];
    const float* Win  = (const float*)d_in[1];
    const float* bin  = (const float*)d_in[2];
    const float* wdw  = (const float*)d_in[3];
    const float* bdw  = (const float*)d_in[4];
    const float* Alog = (const float*)d_in[5];
    const float* Dp   = (const float*)d_in[6];
    const float* Wx   = (const float*)d_in[7];
    const float* Wd   = (const float*)d_in[8];
    const float* bdl  = (const float*)d_in[9];
    const float* lng  = (const float*)d_in[10];
    const float* lnb  = (const float*)d_in[11];
    const float* Wout = (const float*)d_in[12];
    float* out = (float*)d_out;

    float* ws    = (float*)d_ws;
    float* y4    = ws + F_Y4;
    float* xx    = ws + F_XX;    // aliases y4 (dead before y4 written)
    float* zs    = ws + F_ZS;
    float* xt    = ws + F_XT;
    float* xdbl  = ws + F_XDBL;
    float* Pbuf  = ws + F_PBUF;
    float* Hbuf  = ws + F_HBUF;

    k1_inproj<<<288, 256, 0, stream>>>(x, Win, bin, xx, zs);
    k2_conv<<<1152, 192, 0, stream>>>(xx, wdw, bdw, xt);
    k3_xdbl<<<384, 192, 0, stream>>>(xt, Wx, xdbl);
    k4_pass1<<<768, 192, 0, stream>>>(xt, xdbl, Wd, bdl, Alog, Pbuf, Hbuf);
    k4_pass2<<<96, 256, 0, stream>>>(Pbuf, Hbuf);
    k4_pass3<<<768, 192, 0, stream>>>(xt, xdbl, Wd, bdl, Alog, Dp, Hbuf, y4);
    k5_out<<<288, 256, 0, stream>>>(y4, zs, lng, lnb, Wout, out);
}

// Round 3
// 378.448 us; speedup vs baseline: 1.3630x; 1.0193x over previous
//
#include <hip/hip_runtime.h>
#include <math.h>

#define CIN 96
#define D2 192
#define D4 768
#define LL 9216
#define NN 16
#define NCH 192      /* chunks per direction */
#define CLEN 48      /* steps per chunk */

// ---- workspace layout (float offsets) ----
#define SZ_Y2    (2u*2u*9216u*192u)      //  7,077,888
#define SZ_BL    (2u*9216u*192u)         //  3,538,944
#define SZ_XDBL  (2u*9216u*38u)          //    700,416
#define SZ_S     (2u*4u*192u*192u)       //    294,912
#define SZ_H     (2u*4u*192u*192u*16u)   //  4,718,592
#define F_Y2     0u
#define F_XX     0u                       /* alias: xx dead before y2 written */
#define F_ZS     (F_Y2 + SZ_Y2)
#define F_XT     (F_ZS + SZ_BL)
#define F_XDBL   (F_XT + SZ_BL)
#define F_SBUF   (F_XDBL + SZ_XDBL)
#define F_HBUF   (F_SBUF + SZ_S)

__device__ __forceinline__ float silu_f(float z) {
    return z / (1.0f + __expf(-z));
}

// powers p[n] = e1^(n+1), dependency depth <= 4
__device__ __forceinline__ void pow_tree(float e1, float p[16]) {
    p[0] = e1;
    p[1] = e1 * e1;
    p[2] = p[1] * e1;
    p[3] = p[1] * p[1];
    p[4] = p[3] * e1;
    p[5] = p[3] * p[1];
    p[6] = p[3] * p[2];
    p[7] = p[3] * p[3];
    p[8] = p[7] * e1;
    p[9] = p[7] * p[1];
    p[10] = p[7] * p[2];
    p[11] = p[7] * p[3];
    p[12] = p[7] * p[4];
    p[13] = p[7] * p[5];
    p[14] = p[7] * p[6];
    p[15] = p[7] * p[7];
}

// K1: xz = x @ W_in + b_in; first half -> xx (b,192,L), silu(second half) -> zs (b,L,192)
__global__ __launch_bounds__(256) void k1_inproj(
    const float* __restrict__ x, const float* __restrict__ Win,
    const float* __restrict__ bin, float* __restrict__ xx, float* __restrict__ zs)
{
    __shared__ float xs[96][68];
    __shared__ float wsm[96][68];
    int tid = threadIdx.x;
    int gl0 = blockIdx.x * 64;
    int b = gl0 / LL;
    int l0 = gl0 % LL;

    for (int i = tid; i < 96 * 64; i += 256) {
        int k = i >> 6, li = i & 63;
        xs[k][li] = x[(size_t)(b * 96 + k) * LL + l0 + li];
    }
    int lg = tid >> 4;
    int eg = tid & 15;
    for (int ech = 0; ech < 384; ech += 64) {
        __syncthreads();
        for (int i = tid; i < 96 * 64; i += 256) {
            int k = i >> 6, e = i & 63;
            wsm[k][e] = Win[k * 384 + ech + e];
        }
        __syncthreads();
        float acc[4][4];
#pragma unroll
        for (int i = 0; i < 4; i++)
#pragma unroll
            for (int j = 0; j < 4; j++) acc[i][j] = 0.f;
        for (int k = 0; k < 96; k++) {
            float4 xv = *(const float4*)&xs[k][lg * 4];
            float4 wv = *(const float4*)&wsm[k][eg * 4];
            float xa[4] = {xv.x, xv.y, xv.z, xv.w};
            float wa[4] = {wv.x, wv.y, wv.z, wv.w};
#pragma unroll
            for (int i = 0; i < 4; i++)
#pragma unroll
                for (int j = 0; j < 4; j++) acc[i][j] += xa[i] * wa[j];
        }
        int e0 = ech + eg * 4;
        if (e0 < 192) {
#pragma unroll
            for (int j = 0; j < 4; j++) {
                int e = e0 + j;
                float bb = bin[e];
                float4 v = {acc[0][j] + bb, acc[1][j] + bb, acc[2][j] + bb, acc[3][j] + bb};
                *(float4*)&xx[(size_t)(b * 192 + e) * LL + l0 + lg * 4] = v;
            }
        } else {
#pragma unroll
            for (int i = 0; i < 4; i++) {
                int l = l0 + lg * 4 + i;
                float4 v;
                v.x = silu_f(acc[i][0] + bin[e0 + 0]);
                v.y = silu_f(acc[i][1] + bin[e0 + 1]);
                v.z = silu_f(acc[i][2] + bin[e0 + 2]);
                v.w = silu_f(acc[i][3] + bin[e0 + 3]);
                *(float4*)&zs[((size_t)b * LL + l) * 192 + (e0 - 192)] = v;
            }
        }
    }
}

// K2: depthwise 3x3 conv + bias + silu, fused transpose: xx (b,192,96,96) -> xt (b,L,192)
__global__ __launch_bounds__(192) void k2_conv(
    const float* __restrict__ xx, const float* __restrict__ wdw,
    const float* __restrict__ bdw, float* __restrict__ xt)
{
    __shared__ float tile[32][97];
    __shared__ float wsm[32][9];
    __shared__ float bs[32];
    int tid = threadIdx.x;
    int bid = blockIdx.x;
    int h = bid % 96;
    int r = bid / 96;
    int dg = r % 6;
    int b = r / 6;

    for (int i = tid; i < 288; i += 192) wsm[i / 9][i % 9] = wdw[(dg * 32 + i / 9) * 9 + (i % 9)];
    if (tid < 32) bs[tid] = bdw[dg * 32 + tid];
    __syncthreads();

    int w = tid % 96;
    int dhalf = tid / 96;
    for (int p = 0; p < 16; p++) {
        int dsub = 2 * p + dhalf;
        const float* base = xx + (size_t)(b * 192 + dg * 32 + dsub) * LL;
        float acc = bs[dsub];
#pragma unroll
        for (int kh = 0; kh < 3; kh++) {
            int hh = h + kh - 1;
            if (hh < 0 || hh >= 96) continue;
            const float* row = base + hh * 96;
#pragma unroll
            for (int kw = 0; kw < 3; kw++) {
                int ww = w + kw - 1;
                if (ww < 0 || ww >= 96) continue;
                acc += row[ww] * wsm[dsub][kh * 3 + kw];
            }
        }
        tile[dsub][w] = silu_f(acc);
    }
    __syncthreads();
    for (int i = tid; i < 768; i += 192) {
        int q = i & 7, ls = i >> 3;
        float4 v = {tile[q * 4 + 0][ls], tile[q * 4 + 1][ls], tile[q * 4 + 2][ls], tile[q * 4 + 3][ls]};
        *(float4*)&xt[((size_t)b * LL + h * 96 + ls) * 192 + dg * 32 + q * 4] = v;
    }
}

// K3: xdbl[b,l,:38] = xt[b,l,:] @ (Wx[0:192]+Wx[192:384]) + xt[b,flip(l),:] @ (Wx[384:576]+Wx[576:768])
__global__ __launch_bounds__(192) void k3_xdbl(
    const float* __restrict__ xt, const float* __restrict__ Wx,
    float* __restrict__ xdbl)
{
    __shared__ float wf0[192][40];
    __shared__ float wf1[192][40];
    int tid = threadIdx.x;
    int bid = blockIdx.x;
    int b = bid / 192;
    int l0 = (bid % 192) * 48;

    for (int i = tid; i < 192 * 40; i += 192) {
        int d = i / 40, j = i % 40;
        float v0 = 0.f, v1 = 0.f;
        if (j < 38) {
            v0 = Wx[d * 38 + j] + Wx[(d + 192) * 38 + j];
            v1 = Wx[(d + 384) * 38 + j] + Wx[(d + 576) * 38 + j];
        }
        wf0[d][j] = v0;
        wf1[d][j] = v1;
    }
    __syncthreads();
    int lig = tid / 8, jg = tid % 8;
    int li0 = l0 + lig * 2;
    int j0 = jg * 6;
    const float* xf0 = xt + ((size_t)b * LL + li0) * 192;
    const float* xf1 = xf0 + 192;
    const float* xr0 = xt + ((size_t)b * LL + (LL - 1 - li0)) * 192;
    const float* xr1 = xr0 - 192;
    float acc0[6], acc1[6];
#pragma unroll
    for (int j = 0; j < 6; j++) { acc0[j] = 0.f; acc1[j] = 0.f; }
    for (int d = 0; d < 192; d++) {
        float x0 = xf0[d], x1 = xf1[d];
        float r0 = xr0[d], r1 = xr1[d];
        float w0[6], w1[6];
        *(float2*)&w0[0] = *(const float2*)&wf0[d][j0];
        *(float2*)&w0[2] = *(const float2*)&wf0[d][j0 + 2];
        *(float2*)&w0[4] = *(const float2*)&wf0[d][j0 + 4];
        *(float2*)&w1[0] = *(const float2*)&wf1[d][j0];
        *(float2*)&w1[2] = *(const float2*)&wf1[d][j0 + 2];
        *(float2*)&w1[4] = *(const float2*)&wf1[d][j0 + 4];
#pragma unroll
        for (int j = 0; j < 6; j++) {
            acc0[j] += x0 * w0[j] + r0 * w1[j];
            acc1[j] += x1 * w0[j] + r1 * w1[j];
        }
    }
#pragma unroll
    for (int j = 0; j < 6; j++) {
        int jj = j0 + j;
        if (jj < 38) {
            xdbl[((size_t)b * LL + li0) * 38 + jj] = acc0[j];
            xdbl[((size_t)b * LL + li0 + 1) * 38 + jj] = acc1[j];
        }
    }
}

// K4 pass1: per-chunk local scan for a DIRECTION PAIR (2 dirs/thread), h from 0.
// Emits S (sum of delta) and h_local. Grid: b(2) x pair(2) x chunk(192).
__global__ __launch_bounds__(192, 3) void k4_pass1(
    const float* __restrict__ xt, const float* __restrict__ xdbl,
    const float* __restrict__ Wd, const float* __restrict__ bdl,
    const float* __restrict__ Alog,
    float* __restrict__ Sbuf, float* __restrict__ Hbuf)
{
    __shared__ float Bt[CLEN][16];
    __shared__ float Dt[CLEN][6];
    int tid = threadIdx.x;
    int bid = blockIdx.x;
    int k = bid % NCH;
    int r = bid / NCH;
    int pair = r & 1;
    int b = r >> 1;
    int l0 = k * CLEN;
    for (int i = tid; i < CLEN * 16; i += 192) {
        int t = i >> 4, n = i & 15;
        Bt[t][n] = xdbl[((size_t)b * LL + l0 + t) * 38 + 6 + n];
    }
    for (int i = tid; i < CLEN * 6; i += 192) {
        int t = i / 6, rr = i - 6 * t;
        Dt[t][rr] = xdbl[((size_t)b * LL + l0 + t) * 38 + rr];
    }
    __syncthreads();
    int c = tid;
    int dA = (2 * pair) * 192 + c;
    int dB = dA + 192;
    float a0A = -__expf(Alog[dA * 16]);
    float a0B = -__expf(Alog[dB * 16]);
    bool fast = true;
    for (int n = 1; n < 16; n++) {
        float aA = -__expf(Alog[dA * 16 + n]);
        float aB = -__expf(Alog[dB * 16 + n]);
        float tA = (n + 1) * a0A, tB = (n + 1) * a0B;
        fast = fast && (fabsf(aA - tA) <= 1e-5f * fabsf(tA))
                    && (fabsf(aB - tB) <= 1e-5f * fabsf(tB));
    }
    float wdA[6], wdB[6];
#pragma unroll
    for (int rr = 0; rr < 6; rr++) { wdA[rr] = Wd[rr * 768 + dA]; wdB[rr] = Wd[rr * 768 + dB]; }
    float bdeA = bdl[dA], bdeB = bdl[dB];
    float hA[16], hB[16];
#pragma unroll
    for (int n = 0; n < 16; n++) { hA[n] = 0.f; hB[n] = 0.f; }
    float SA = 0.f, SB = 0.f;
    const float* xtp = xt + (size_t)b * LL * 192 + c;
    for (int t = 0; t < CLEN; t++) {
        float sA = bdeA, sB = bdeB;
#pragma unroll
        for (int rr = 0; rr < 6; rr++) {
            float dv = Dt[t][rr];
            sA += dv * wdA[rr]; sB += dv * wdB[rr];
        }
        float dtA = (sA > 20.f) ? sA : __logf(1.f + __expf(sA));
        float dtB = (sB > 20.f) ? sB : __logf(1.f + __expf(sB));
        SA += dtA; SB += dtB;
        int lp = (pair == 0) ? (l0 + t) : (LL - 1 - (l0 + t));
        float u = xtp[(size_t)lp * 192];
        float duA = dtA * u, duB = dtB * u;
        float Bv[16];
        *(float4*)&Bv[0]  = *(const float4*)&Bt[t][0];
        *(float4*)&Bv[4]  = *(const float4*)&Bt[t][4];
        *(float4*)&Bv[8]  = *(const float4*)&Bt[t][8];
        *(float4*)&Bv[12] = *(const float4*)&Bt[t][12];
        if (fast) {
            float p[16];
            pow_tree(__expf(dtA * a0A), p);
#pragma unroll
            for (int n = 0; n < 16; n++) hA[n] = p[n] * hA[n] + duA * Bv[n];
            pow_tree(__expf(dtB * a0B), p);
#pragma unroll
            for (int n = 0; n < 16; n++) hB[n] = p[n] * hB[n] + duB * Bv[n];
        } else {
#pragma unroll
            for (int n = 0; n < 16; n++) {
                float eA = __expf(dtA * (-__expf(Alog[dA * 16 + n])));
                float eB = __expf(dtB * (-__expf(Alog[dB * 16 + n])));
                hA[n] = eA * hA[n] + duA * Bv[n];
                hB[n] = eB * hB[n] + duB * Bv[n];
            }
        }
    }
    size_t baseA = ((((size_t)(b * 4 + 2 * pair)) * NCH + k) * 192 + c) * 16;
    size_t baseB = ((((size_t)(b * 4 + 2 * pair + 1)) * NCH + k) * 192 + c) * 16;
#pragma unroll
    for (int n = 0; n < 16; n++) { Hbuf[baseA + n] = hA[n]; Hbuf[baseB + n] = hB[n]; }
    Sbuf[(((size_t)(b * 4 + 2 * pair)) * NCH + k) * 192 + c] = SA;
    Sbuf[(((size_t)(b * 4 + 2 * pair + 1)) * NCH + k) * 192 + c] = SB;
}

// K4 pass2: scan over chunk summaries; Hbuf[k] := h_start; P = exp(a*S) on the fly
__global__ __launch_bounds__(256) void k4_pass2(
    const float* __restrict__ Sbuf, const float* __restrict__ Alog,
    float* __restrict__ Hbuf)
{
    int lane = blockIdx.x * 256 + threadIdx.x;  // 24576
    int bd = lane / 3072;
    int cn = lane % 3072;
    int c = cn >> 4, n = cn & 15;
    int dir = bd & 3;
    float an = -__expf(Alog[(dir * 192 + c) * 16 + n]);
    float h = 0.f;
#pragma unroll 8
    for (int k = 0; k < NCH; k++) {
        size_t sidx = ((size_t)bd * NCH + k) * 192 + c;
        float S = Sbuf[sidx];
        size_t idx = sidx * 16 + n;
        float hl = Hbuf[idx];
        float P = __expf(an * S);
        Hbuf[idx] = h;
        h = P * h + hl;
    }
}

// K4 pass3: replay chunk from h_start for a direction pair; write pair-summed y2
__global__ __launch_bounds__(192, 3) void k4_pass3(
    const float* __restrict__ xt, const float* __restrict__ xdbl,
    const float* __restrict__ Wd, const float* __restrict__ bdl,
    const float* __restrict__ Alog, const float* __restrict__ Dp,
    const float* __restrict__ Hbuf, float* __restrict__ y2)
{
    __shared__ float Bt[CLEN][16];
    __shared__ float Ct[CLEN][16];
    __shared__ float Dt[CLEN][6];
    int tid = threadIdx.x;
    int bid = blockIdx.x;
    int k = bid % NCH;
    int r = bid / NCH;
    int pair = r & 1;
    int b = r >> 1;
    int l0 = k * CLEN;
    for (int i = tid; i < CLEN * 16; i += 192) {
        int t = i >> 4, n = i & 15;
        size_t rb = ((size_t)b * LL + l0 + t) * 38;
        Bt[t][n] = xdbl[rb + 6 + n];
        Ct[t][n] = xdbl[rb + 22 + n];
    }
    for (int i = tid; i < CLEN * 6; i += 192) {
        int t = i / 6, rr = i - 6 * t;
        Dt[t][rr] = xdbl[((size_t)b * LL + l0 + t) * 38 + rr];
    }
    __syncthreads();
    int c = tid;
    int dA = (2 * pair) * 192 + c;
    int dB = dA + 192;
    float a0A = -__expf(Alog[dA * 16]);
    float a0B = -__expf(Alog[dB * 16]);
    bool fast = true;
    for (int n = 1; n < 16; n++) {
        float aA = -__expf(Alog[dA * 16 + n]);
        float aB = -__expf(Alog[dB * 16 + n]);
        float tA = (n + 1) * a0A, tB = (n + 1) * a0B;
        fast = fast && (fabsf(aA - tA) <= 1e-5f * fabsf(tA))
                    && (fabsf(aB - tB) <= 1e-5f * fabsf(tB));
    }
    float wdA[6], wdB[6];
#pragma unroll
    for (int rr = 0; rr < 6; rr++) { wdA[rr] = Wd[rr * 768 + dA]; wdB[rr] = Wd[rr * 768 + dB]; }
    float bdeA = bdl[dA], bdeB = bdl[dB];
    float DvA = Dp[dA], DvB = Dp[dB];
    float hA[16], hB[16];
    size_t baseA = ((((size_t)(b * 4 + 2 * pair)) * NCH + k) * 192 + c) * 16;
    size_t baseB = ((((size_t)(b * 4 + 2 * pair + 1)) * NCH + k) * 192 + c) * 16;
#pragma unroll
    for (int n = 0; n < 16; n++) { hA[n] = Hbuf[baseA + n]; hB[n] = Hbuf[baseB + n]; }
    const float* xtp = xt + (size_t)b * LL * 192 + c;
    float* y2p = y2 + ((size_t)(b * 2 + pair)) * LL * 192 + c;
    for (int t = 0; t < CLEN; t++) {
        float sA = bdeA, sB = bdeB;
#pragma unroll
        for (int rr = 0; rr < 6; rr++) {
            float dv = Dt[t][rr];
            sA += dv * wdA[rr]; sB += dv * wdB[rr];
        }
        float dtA = (sA > 20.f) ? sA : __logf(1.f + __expf(sA));
        float dtB = (sB > 20.f) ? sB : __logf(1.f + __expf(sB));
        int lp = (pair == 0) ? (l0 + t) : (LL - 1 - (l0 + t));
        float u = xtp[(size_t)lp * 192];
        float duA = dtA * u, duB = dtB * u;
        float Bv[16], Cv[16];
        *(float4*)&Bv[0]  = *(const float4*)&Bt[t][0];
        *(float4*)&Bv[4]  = *(const float4*)&Bt[t][4];
        *(float4*)&Bv[8]  = *(const float4*)&Bt[t][8];
        *(float4*)&Bv[12] = *(const float4*)&Bt[t][12];
        *(float4*)&Cv[0]  = *(const float4*)&Ct[t][0];
        *(float4*)&Cv[4]  = *(const float4*)&Ct[t][4];
        *(float4*)&Cv[8]  = *(const float4*)&Ct[t][8];
        *(float4*)&Cv[12] = *(const float4*)&Ct[t][12];
        float yv = (DvA + DvB) * u;  // Dv*u contribution of both dirs
        if (fast) {
            float p[16];
            pow_tree(__expf(dtA * a0A), p);
#pragma unroll
            for (int n = 0; n < 16; n++) {
                hA[n] = p[n] * hA[n] + duA * Bv[n];
                yv += hA[n] * Cv[n];
            }
            pow_tree(__expf(dtB * a0B), p);
#pragma unroll
            for (int n = 0; n < 16; n++) {
                hB[n] = p[n] * hB[n] + duB * Bv[n];
                yv += hB[n] * Cv[n];
            }
        } else {
#pragma unroll
            for (int n = 0; n < 16; n++) {
                float eA = __expf(dtA * (-__expf(Alog[dA * 16 + n])));
                float eB = __expf(dtB * (-__expf(Alog[dB * 16 + n])));
                hA[n] = eA * hA[n] + duA * Bv[n];
                hB[n] = eB * hB[n] + duB * Bv[n];
                yv += hA[n] * Cv[n] + hB[n] * Cv[n];
            }
        }
        y2p[(size_t)lp * 192] = yv;
    }
}

// K5: yh = y2 pair0 + pair1; LayerNorm(192); * silu(z); @ W_out -> out (b,96,H,W)
__global__ __launch_bounds__(256) void k5_out(
    const float* __restrict__ y2, const float* __restrict__ zs,
    const float* __restrict__ lng, const float* __restrict__ lnb,
    const float* __restrict__ Wout, float* __restrict__ out)
{
    __shared__ float acts[64][194];
    __shared__ float wsh[32][100];
    int tid = threadIdx.x;
    int wv = tid >> 6;
    int lane = tid & 63;
    int gl0 = blockIdx.x * 64;
    int b = gl0 / LL;
    int l0 = gl0 % LL;
    const size_t ds2 = (size_t)LL * 192;

    for (int i = 0; i < 16; i++) {
        int rrow = wv * 16 + i;
        int l = l0 + rrow;
        float yv[3], zv[3];
        float s1 = 0.f, s2 = 0.f;
#pragma unroll
        for (int kk = 0; kk < 3; kk++) {
            int c = lane + kk * 64;
            size_t off = ((size_t)(b * 2) * LL + l) * 192 + c;
            float y = y2[off] + y2[off + ds2];
            yv[kk] = y;
            zv[kk] = zs[((size_t)b * LL + l) * 192 + c];
            s1 += y; s2 += y * y;
        }
#pragma unroll
        for (int o = 32; o; o >>= 1) {
            s1 += __shfl_xor(s1, o, 64);
            s2 += __shfl_xor(s2, o, 64);
        }
        float mean = s1 * (1.f / 192.f);
        float var = s2 * (1.f / 192.f) - mean * mean;
        float rs = rsqrtf(var + 1e-5f);
#pragma unroll
        for (int kk = 0; kk < 3; kk++) {
            int c = lane + kk * 64;
            float yn = (yv[kk] - mean) * rs * lng[c] + lnb[c];
            acts[rrow][c] = yn * zv[kk];
        }
    }

    int ty = tid >> 4;
    int tx = tid & 15;
    float o[4][6];
#pragma unroll
    for (int i = 0; i < 4; i++)
#pragma unroll
        for (int j = 0; j < 6; j++) o[i][j] = 0.f;

    for (int kc = 0; kc < 192; kc += 32) {
        __syncthreads();
        for (int i = tid; i < 3072; i += 256)
            wsh[i / 96][i % 96] = Wout[(kc + i / 96) * 96 + i % 96];
        __syncthreads();
        for (int kk = 0; kk < 32; kk++) {
            float av[4];
#pragma unroll
            for (int i = 0; i < 4; i++) av[i] = acts[ty * 4 + i][kc + kk];
            float wvv[6];
#pragma unroll
            for (int j = 0; j < 6; j++) wvv[j] = wsh[kk][tx * 6 + j];
#pragma unroll
            for (int i = 0; i < 4; i++)
#pragma unroll
                for (int j = 0; j < 6; j++) o[i][j] += av[i] * wvv[j];
        }
    }
#pragma unroll
    for (int i = 0; i < 4; i++) {
        int l = l0 + ty * 4 + i;
#pragma unroll
        for (int j = 0; j < 6; j++) {
            int n = tx * 6 + j;
            out[((size_t)(b * 96) + n) * LL + l] = o[i][j];
        }
    }
}

extern "C" void kernel_launch(void* const* d_in, const int* in_sizes, int n_in,
                              void* d_out, int out_size, void* d_ws, size_t ws_size,
                              hipStream_t stream)
{
    const float* x    = (const float*)d_in[0];
    const float* Win  = (const float*)d_in[1];
    const float* bin  = (const float*)d_in[2];
    const float* wdw  = (const float*)d_in[3];
    const float* bdw  = (const float*)d_in[4];
    const float* Alog = (const float*)d_in[5];
    const float* Dp   = (const float*)d_in[6];
    const float* Wx   = (const float*)d_in[7];
    const float* Wd   = (const float*)d_in[8];
    const float* bdl  = (const float*)d_in[9];
    const float* lng  = (const float*)d_in[10];
    const float* lnb  = (const float*)d_in[11];
    const float* Wout = (const float*)d_in[12];
    float* out = (float*)d_out;

    float* ws    = (float*)d_ws;
    float* y2    = ws + F_Y2;
    float* xx    = ws + F_XX;    // aliases y2 (dead before y2 written)
    float* zs    = ws + F_ZS;
    float* xt    = ws + F_XT;
    float* xdbl  = ws + F_XDBL;
    float* Sbuf  = ws + F_SBUF;
    float* Hbuf  = ws + F_HBUF;

    k1_inproj<<<288, 256, 0, stream>>>(x, Win, bin, xx, zs);
    k2_conv<<<1152, 192, 0, stream>>>(xx, wdw, bdw, xt);
    k3_xdbl<<<384, 192, 0, stream>>>(xt, Wx, xdbl);
    k4_pass1<<<768, 192, 0, stream>>>(xt, xdbl, Wd, bdl, Alog, Sbuf, Hbuf);
    k4_pass2<<<96, 256, 0, stream>>>(Sbuf, Alog, Hbuf);
    k4_pass3<<<768, 192, 0, stream>>>(xt, xdbl, Wd, bdl, Alog, Dp, Hbuf, y2);
    k5_out<<<288, 256, 0, stream>>>(y2, zs, lng, lnb, Wout, out);
}

// Round 4
// 357.931 us; speedup vs baseline: 1.4412x; 1.0573x over previous
//
#include <hip/hip_runtime.h>
#include <hip/hip_bf16.h>
#include <math.h>

#define CIN 96
#define D2 192
#define D4 768
#define LL 9216
#define NN 16
#define NCH 192      /* chunks per direction */
#define CLEN 48      /* steps per chunk */

// ---- workspace layout (float-slot offsets) ----
// y4 is bf16 (2*4*9216*192 elems = 28.3MB) occupying SZ_Y4SLOT float slots.
#define SZ_Y4SLOT (2u*2u*9216u*192u)     //  7,077,888 float slots (bf16 x2)
#define SZ_BL    (2u*9216u*192u)         //  3,538,944
#define SZ_XDBL  (2u*9216u*38u)          //    700,416
#define SZ_S     (2u*4u*192u*192u)       //    294,912
#define SZ_H     (2u*4u*192u*192u*16u)   //  4,718,592
#define F_Y4     0u
#define F_XX     0u                       /* alias: xx dead before y4 written */
#define F_ZS     (F_Y4 + SZ_Y4SLOT)
#define F_XT     (F_ZS + SZ_BL)
#define F_XDBL   (F_XT + SZ_BL)
#define F_SBUF   (F_XDBL + SZ_XDBL)
#define F_HBUF   (F_SBUF + SZ_S)

__device__ __forceinline__ float silu_f(float z) {
    return z / (1.0f + __expf(-z));
}

// powers p[n] = e1^(n+1), dependency depth <= 4
__device__ __forceinline__ void pow_tree(float e1, float p[16]) {
    p[0] = e1;
    p[1] = e1 * e1;
    p[2] = p[1] * e1;
    p[3] = p[1] * p[1];
    p[4] = p[3] * e1;
    p[5] = p[3] * p[1];
    p[6] = p[3] * p[2];
    p[7] = p[3] * p[3];
    p[8] = p[7] * e1;
    p[9] = p[7] * p[1];
    p[10] = p[7] * p[2];
    p[11] = p[7] * p[3];
    p[12] = p[7] * p[4];
    p[13] = p[7] * p[5];
    p[14] = p[7] * p[6];
    p[15] = p[7] * p[7];
}

// K1: xz = x @ W_in + b_in; first half -> xx (b,192,L), silu(second half) -> zs (b,L,192)
__global__ __launch_bounds__(256) void k1_inproj(
    const float* __restrict__ x, const float* __restrict__ Win,
    const float* __restrict__ bin, float* __restrict__ xx, float* __restrict__ zs)
{
    __shared__ float xs[96][68];
    __shared__ float wsm[96][68];
    int tid = threadIdx.x;
    int gl0 = blockIdx.x * 64;
    int b = gl0 / LL;
    int l0 = gl0 % LL;

    for (int i = tid; i < 96 * 64; i += 256) {
        int k = i >> 6, li = i & 63;
        xs[k][li] = x[(size_t)(b * 96 + k) * LL + l0 + li];
    }
    int lg = tid >> 4;
    int eg = tid & 15;
    for (int ech = 0; ech < 384; ech += 64) {
        __syncthreads();
        for (int i = tid; i < 96 * 64; i += 256) {
            int k = i >> 6, e = i & 63;
            wsm[k][e] = Win[k * 384 + ech + e];
        }
        __syncthreads();
        float acc[4][4];
#pragma unroll
        for (int i = 0; i < 4; i++)
#pragma unroll
            for (int j = 0; j < 4; j++) acc[i][j] = 0.f;
        for (int k = 0; k < 96; k++) {
            float4 xv = *(const float4*)&xs[k][lg * 4];
            float4 wv = *(const float4*)&wsm[k][eg * 4];
            float xa[4] = {xv.x, xv.y, xv.z, xv.w};
            float wa[4] = {wv.x, wv.y, wv.z, wv.w};
#pragma unroll
            for (int i = 0; i < 4; i++)
#pragma unroll
                for (int j = 0; j < 4; j++) acc[i][j] += xa[i] * wa[j];
        }
        int e0 = ech + eg * 4;
        if (e0 < 192) {
#pragma unroll
            for (int j = 0; j < 4; j++) {
                int e = e0 + j;
                float bb = bin[e];
                float4 v = {acc[0][j] + bb, acc[1][j] + bb, acc[2][j] + bb, acc[3][j] + bb};
                *(float4*)&xx[(size_t)(b * 192 + e) * LL + l0 + lg * 4] = v;
            }
        } else {
#pragma unroll
            for (int i = 0; i < 4; i++) {
                int l = l0 + lg * 4 + i;
                float4 v;
                v.x = silu_f(acc[i][0] + bin[e0 + 0]);
                v.y = silu_f(acc[i][1] + bin[e0 + 1]);
                v.z = silu_f(acc[i][2] + bin[e0 + 2]);
                v.w = silu_f(acc[i][3] + bin[e0 + 3]);
                *(float4*)&zs[((size_t)b * LL + l) * 192 + (e0 - 192)] = v;
            }
        }
    }
}

// K2: depthwise 3x3 conv + bias + silu, fused transpose: xx (b,192,96,96) -> xt (b,L,192)
__global__ __launch_bounds__(192) void k2_conv(
    const float* __restrict__ xx, const float* __restrict__ wdw,
    const float* __restrict__ bdw, float* __restrict__ xt)
{
    __shared__ float tile[32][97];
    __shared__ float wsm[32][9];
    __shared__ float bs[32];
    int tid = threadIdx.x;
    int bid = blockIdx.x;
    int h = bid % 96;
    int r = bid / 96;
    int dg = r % 6;
    int b = r / 6;

    for (int i = tid; i < 288; i += 192) wsm[i / 9][i % 9] = wdw[(dg * 32 + i / 9) * 9 + (i % 9)];
    if (tid < 32) bs[tid] = bdw[dg * 32 + tid];
    __syncthreads();

    int w = tid % 96;
    int dhalf = tid / 96;
    for (int p = 0; p < 16; p++) {
        int dsub = 2 * p + dhalf;
        const float* base = xx + (size_t)(b * 192 + dg * 32 + dsub) * LL;
        float acc = bs[dsub];
#pragma unroll
        for (int kh = 0; kh < 3; kh++) {
            int hh = h + kh - 1;
            if (hh < 0 || hh >= 96) continue;
            const float* row = base + hh * 96;
#pragma unroll
            for (int kw = 0; kw < 3; kw++) {
                int ww = w + kw - 1;
                if (ww < 0 || ww >= 96) continue;
                acc += row[ww] * wsm[dsub][kh * 3 + kw];
            }
        }
        tile[dsub][w] = silu_f(acc);
    }
    __syncthreads();
    for (int i = tid; i < 768; i += 192) {
        int q = i & 7, ls = i >> 3;
        float4 v = {tile[q * 4 + 0][ls], tile[q * 4 + 1][ls], tile[q * 4 + 2][ls], tile[q * 4 + 3][ls]};
        *(float4*)&xt[((size_t)b * LL + h * 96 + ls) * 192 + dg * 32 + q * 4] = v;
    }
}

// K3: xdbl[b,l,:38] = xt[b,l,:] @ (Wx[0:192]+Wx[192:384]) + xt[b,flip(l),:] @ (Wx[384:576]+Wx[576:768])
__global__ __launch_bounds__(192) void k3_xdbl(
    const float* __restrict__ xt, const float* __restrict__ Wx,
    float* __restrict__ xdbl)
{
    __shared__ float wf0[192][40];
    __shared__ float wf1[192][40];
    int tid = threadIdx.x;
    int bid = blockIdx.x;
    int b = bid / 192;
    int l0 = (bid % 192) * 48;

    for (int i = tid; i < 192 * 40; i += 192) {
        int d = i / 40, j = i % 40;
        float v0 = 0.f, v1 = 0.f;
        if (j < 38) {
            v0 = Wx[d * 38 + j] + Wx[(d + 192) * 38 + j];
            v1 = Wx[(d + 384) * 38 + j] + Wx[(d + 576) * 38 + j];
        }
        wf0[d][j] = v0;
        wf1[d][j] = v1;
    }
    __syncthreads();
    int lig = tid / 8, jg = tid % 8;
    int li0 = l0 + lig * 2;
    int j0 = jg * 6;
    const float* xf0 = xt + ((size_t)b * LL + li0) * 192;
    const float* xf1 = xf0 + 192;
    const float* xr0 = xt + ((size_t)b * LL + (LL - 1 - li0)) * 192;
    const float* xr1 = xr0 - 192;
    float acc0[6], acc1[6];
#pragma unroll
    for (int j = 0; j < 6; j++) { acc0[j] = 0.f; acc1[j] = 0.f; }
    for (int d = 0; d < 192; d++) {
        float x0 = xf0[d], x1 = xf1[d];
        float r0 = xr0[d], r1 = xr1[d];
        float w0[6], w1[6];
        *(float2*)&w0[0] = *(const float2*)&wf0[d][j0];
        *(float2*)&w0[2] = *(const float2*)&wf0[d][j0 + 2];
        *(float2*)&w0[4] = *(const float2*)&wf0[d][j0 + 4];
        *(float2*)&w1[0] = *(const float2*)&wf1[d][j0];
        *(float2*)&w1[2] = *(const float2*)&wf1[d][j0 + 2];
        *(float2*)&w1[4] = *(const float2*)&wf1[d][j0 + 4];
#pragma unroll
        for (int j = 0; j < 6; j++) {
            acc0[j] += x0 * w0[j] + r0 * w1[j];
            acc1[j] += x1 * w0[j] + r1 * w1[j];
        }
    }
#pragma unroll
    for (int j = 0; j < 6; j++) {
        int jj = j0 + j;
        if (jj < 38) {
            xdbl[((size_t)b * LL + li0) * 38 + jj] = acc0[j];
            xdbl[((size_t)b * LL + li0 + 1) * 38 + jj] = acc1[j];
        }
    }
}

// K4 pass1: per-chunk local scan, SINGLE direction per block, h from 0.
// Emits S (sum of delta) and h_local. Grid: b(2) x dir(4) x chunk(192).
__global__ __launch_bounds__(192, 5) void k4_pass1(
    const float* __restrict__ xt, const float* __restrict__ xdbl,
    const float* __restrict__ Wd, const float* __restrict__ bdl,
    const float* __restrict__ Alog,
    float* __restrict__ Sbuf, float* __restrict__ Hbuf)
{
    __shared__ float Bt[CLEN][16];
    __shared__ float Dt[CLEN][6];
    int tid = threadIdx.x;
    int bid = blockIdx.x;
    int k = bid % NCH;
    int r = bid / NCH;
    int dir = r & 3;
    int b = r >> 2;
    int l0 = k * CLEN;
    for (int i = tid; i < CLEN * 16; i += 192) {
        int t = i >> 4, n = i & 15;
        Bt[t][n] = xdbl[((size_t)b * LL + l0 + t) * 38 + 6 + n];
    }
    for (int i = tid; i < CLEN * 6; i += 192) {
        int t = i / 6, rr = i - 6 * t;
        Dt[t][rr] = xdbl[((size_t)b * LL + l0 + t) * 38 + rr];
    }
    __syncthreads();
    int c = tid;
    int d4 = dir * 192 + c;
    float a0 = -__expf(Alog[d4 * 16]);
    bool fast = true;
    for (int n = 1; n < 16; n++) {
        float an = -__expf(Alog[d4 * 16 + n]);
        float tgt = (n + 1) * a0;
        fast = fast && (fabsf(an - tgt) <= 1e-5f * fabsf(tgt));
    }
    float wd[6];
#pragma unroll
    for (int rr = 0; rr < 6; rr++) wd[rr] = Wd[rr * 768 + d4];
    float bde = bdl[d4];
    float h[16];
#pragma unroll
    for (int n = 0; n < 16; n++) h[n] = 0.f;
    float S = 0.f;
    const float* xtp = xt + (size_t)b * LL * 192 + c;
    if (fast) {
        for (int t = 0; t < CLEN; t++) {
            float s = bde;
#pragma unroll
            for (int rr = 0; rr < 6; rr++) s += Dt[t][rr] * wd[rr];
            float dt = (s > 20.f) ? s : __logf(1.f + __expf(s));
            S += dt;
            int lp = (dir < 2) ? (l0 + t) : (LL - 1 - (l0 + t));
            float u = xtp[(size_t)lp * 192];
            float du = dt * u;
            float Bv[16];
            *(float4*)&Bv[0]  = *(const float4*)&Bt[t][0];
            *(float4*)&Bv[4]  = *(const float4*)&Bt[t][4];
            *(float4*)&Bv[8]  = *(const float4*)&Bt[t][8];
            *(float4*)&Bv[12] = *(const float4*)&Bt[t][12];
            float p[16];
            pow_tree(__expf(dt * a0), p);
#pragma unroll
            for (int n = 0; n < 16; n++) h[n] = p[n] * h[n] + du * Bv[n];
        }
    } else {
        for (int t = 0; t < CLEN; t++) {
            float s = bde;
#pragma unroll
            for (int rr = 0; rr < 6; rr++) s += Dt[t][rr] * wd[rr];
            float dt = (s > 20.f) ? s : __logf(1.f + __expf(s));
            S += dt;
            int lp = (dir < 2) ? (l0 + t) : (LL - 1 - (l0 + t));
            float u = xtp[(size_t)lp * 192];
            float du = dt * u;
#pragma unroll
            for (int n = 0; n < 16; n++) {
                float e = __expf(dt * (-__expf(Alog[d4 * 16 + n])));
                h[n] = e * h[n] + du * Bt[t][n];
            }
        }
    }
    int bd = b * 4 + dir;
    size_t base = (((size_t)bd * NCH + k) * 192 + c) * 16;
#pragma unroll
    for (int n = 0; n < 16; n++) Hbuf[base + n] = h[n];
    Sbuf[((size_t)bd * NCH + k) * 192 + c] = S;
}

// K4 pass2: scan over chunk summaries; Hbuf[k] := h_start; P = exp(a*S) on the fly
__global__ __launch_bounds__(256) void k4_pass2(
    const float* __restrict__ Sbuf, const float* __restrict__ Alog,
    float* __restrict__ Hbuf)
{
    int lane = blockIdx.x * 256 + threadIdx.x;  // 24576
    int bd = lane / 3072;
    int cn = lane % 3072;
    int c = cn >> 4, n = cn & 15;
    int dir = bd & 3;
    float an = -__expf(Alog[(dir * 192 + c) * 16 + n]);
    float h = 0.f;
#pragma unroll 8
    for (int k = 0; k < NCH; k++) {
        size_t sidx = ((size_t)bd * NCH + k) * 192 + c;
        float S = Sbuf[sidx];
        size_t idx = sidx * 16 + n;
        float hl = Hbuf[idx];
        float P = __expf(an * S);
        Hbuf[idx] = h;
        h = P * h + hl;
    }
}

// K4 pass3: replay chunk from h_start, SINGLE direction per block; y -> bf16 slab (b,dir,Lphys,192)
__global__ __launch_bounds__(192, 5) void k4_pass3(
    const float* __restrict__ xt, const float* __restrict__ xdbl,
    const float* __restrict__ Wd, const float* __restrict__ bdl,
    const float* __restrict__ Alog, const float* __restrict__ Dp,
    const float* __restrict__ Hbuf, __hip_bfloat16* __restrict__ y4)
{
    __shared__ float Bt[CLEN][16];
    __shared__ float Ct[CLEN][16];
    __shared__ float Dt[CLEN][6];
    int tid = threadIdx.x;
    int bid = blockIdx.x;
    int k = bid % NCH;
    int r = bid / NCH;
    int dir = r & 3;
    int b = r >> 2;
    int l0 = k * CLEN;
    for (int i = tid; i < CLEN * 16; i += 192) {
        int t = i >> 4, n = i & 15;
        size_t rb = ((size_t)b * LL + l0 + t) * 38;
        Bt[t][n] = xdbl[rb + 6 + n];
        Ct[t][n] = xdbl[rb + 22 + n];
    }
    for (int i = tid; i < CLEN * 6; i += 192) {
        int t = i / 6, rr = i - 6 * t;
        Dt[t][rr] = xdbl[((size_t)b * LL + l0 + t) * 38 + rr];
    }
    __syncthreads();
    int c = tid;
    int d4 = dir * 192 + c;
    float a0 = -__expf(Alog[d4 * 16]);
    bool fast = true;
    for (int n = 1; n < 16; n++) {
        float an = -__expf(Alog[d4 * 16 + n]);
        float tgt = (n + 1) * a0;
        fast = fast && (fabsf(an - tgt) <= 1e-5f * fabsf(tgt));
    }
    float wd[6];
#pragma unroll
    for (int rr = 0; rr < 6; rr++) wd[rr] = Wd[rr * 768 + d4];
    float bde = bdl[d4];
    float Dv = Dp[d4];
    int bd = b * 4 + dir;
    float h[16];
    size_t base = (((size_t)bd * NCH + k) * 192 + c) * 16;
#pragma unroll
    for (int n = 0; n < 16; n++) h[n] = Hbuf[base + n];
    const float* xtp = xt + (size_t)b * LL * 192 + c;
    __hip_bfloat16* yp = y4 + (size_t)bd * LL * 192 + c;
    if (fast) {
        for (int t = 0; t < CLEN; t++) {
            float s = bde;
#pragma unroll
            for (int rr = 0; rr < 6; rr++) s += Dt[t][rr] * wd[rr];
            float dt = (s > 20.f) ? s : __logf(1.f + __expf(s));
            int lp = (dir < 2) ? (l0 + t) : (LL - 1 - (l0 + t));
            float u = xtp[(size_t)lp * 192];
            float du = dt * u;
            float Bv[16], Cv[16];
            *(float4*)&Bv[0]  = *(const float4*)&Bt[t][0];
            *(float4*)&Bv[4]  = *(const float4*)&Bt[t][4];
            *(float4*)&Bv[8]  = *(const float4*)&Bt[t][8];
            *(float4*)&Bv[12] = *(const float4*)&Bt[t][12];
            *(float4*)&Cv[0]  = *(const float4*)&Ct[t][0];
            *(float4*)&Cv[4]  = *(const float4*)&Ct[t][4];
            *(float4*)&Cv[8]  = *(const float4*)&Ct[t][8];
            *(float4*)&Cv[12] = *(const float4*)&Ct[t][12];
            float p[16];
            pow_tree(__expf(dt * a0), p);
            float y0, y1, y2a, y3;
            h[0] = p[0] * h[0] + du * Bv[0];  y0 = h[0] * Cv[0];
            h[1] = p[1] * h[1] + du * Bv[1];  y1 = h[1] * Cv[1];
            h[2] = p[2] * h[2] + du * Bv[2];  y2a = h[2] * Cv[2];
            h[3] = p[3] * h[3] + du * Bv[3];  y3 = h[3] * Cv[3];
#pragma unroll
            for (int n = 4; n < 16; n += 4) {
                h[n] = p[n] * h[n] + du * Bv[n];          y0 += h[n] * Cv[n];
                h[n + 1] = p[n + 1] * h[n + 1] + du * Bv[n + 1]; y1 += h[n + 1] * Cv[n + 1];
                h[n + 2] = p[n + 2] * h[n + 2] + du * Bv[n + 2]; y2a += h[n + 2] * Cv[n + 2];
                h[n + 3] = p[n + 3] * h[n + 3] + du * Bv[n + 3]; y3 += h[n + 3] * Cv[n + 3];
            }
            float yv = (y0 + y1) + (y2a + y3) + Dv * u;
            yp[(size_t)lp * 192] = __float2bfloat16(yv);
        }
    } else {
        for (int t = 0; t < CLEN; t++) {
            float s = bde;
#pragma unroll
            for (int rr = 0; rr < 6; rr++) s += Dt[t][rr] * wd[rr];
            float dt = (s > 20.f) ? s : __logf(1.f + __expf(s));
            int lp = (dir < 2) ? (l0 + t) : (LL - 1 - (l0 + t));
            float u = xtp[(size_t)lp * 192];
            float du = dt * u;
            float yv = Dv * u;
#pragma unroll
            for (int n = 0; n < 16; n++) {
                float e = __expf(dt * (-__expf(Alog[d4 * 16 + n])));
                h[n] = e * h[n] + du * Bt[t][n];
                yv += h[n] * Ct[t][n];
            }
            yp[(size_t)lp * 192] = __float2bfloat16(yv);
        }
    }
}

// K5: yh = sum of 4 bf16 slabs; LayerNorm(192); * silu(z); @ W_out -> out (b,96,H,W)
__global__ __launch_bounds__(256) void k5_out(
    const __hip_bfloat16* __restrict__ y4, const float* __restrict__ zs,
    const float* __restrict__ lng, const float* __restrict__ lnb,
    const float* __restrict__ Wout, float* __restrict__ out)
{
    __shared__ float acts[64][194];
    __shared__ float wsh[32][100];
    int tid = threadIdx.x;
    int wv = tid >> 6;
    int lane = tid & 63;
    int gl0 = blockIdx.x * 64;
    int b = gl0 / LL;
    int l0 = gl0 % LL;
    const size_t ds = (size_t)LL * 192;

    for (int i = 0; i < 16; i++) {
        int rrow = wv * 16 + i;
        int l = l0 + rrow;
        float yv[3], zv[3];
        float s1 = 0.f, s2 = 0.f;
#pragma unroll
        for (int kk = 0; kk < 3; kk++) {
            int c = lane + kk * 64;
            size_t off = ((size_t)(b * 4) * LL + l) * 192 + c;
            float y = __bfloat162float(y4[off]) + __bfloat162float(y4[off + ds])
                    + __bfloat162float(y4[off + 2 * ds]) + __bfloat162float(y4[off + 3 * ds]);
            yv[kk] = y;
            zv[kk] = zs[((size_t)b * LL + l) * 192 + c];
            s1 += y; s2 += y * y;
        }
#pragma unroll
        for (int o = 32; o; o >>= 1) {
            s1 += __shfl_xor(s1, o, 64);
            s2 += __shfl_xor(s2, o, 64);
        }
        float mean = s1 * (1.f / 192.f);
        float var = s2 * (1.f / 192.f) - mean * mean;
        float rs = rsqrtf(var + 1e-5f);
#pragma unroll
        for (int kk = 0; kk < 3; kk++) {
            int c = lane + kk * 64;
            float yn = (yv[kk] - mean) * rs * lng[c] + lnb[c];
            acts[rrow][c] = yn * zv[kk];
        }
    }

    int ty = tid >> 4;
    int tx = tid & 15;
    float o[4][6];
#pragma unroll
    for (int i = 0; i < 4; i++)
#pragma unroll
        for (int j = 0; j < 6; j++) o[i][j] = 0.f;

    for (int kc = 0; kc < 192; kc += 32) {
        __syncthreads();
        for (int i = tid; i < 3072; i += 256)
            wsh[i / 96][i % 96] = Wout[(kc + i / 96) * 96 + i % 96];
        __syncthreads();
        for (int kk = 0; kk < 32; kk++) {
            float av[4];
#pragma unroll
            for (int i = 0; i < 4; i++) av[i] = acts[ty * 4 + i][kc + kk];
            float wvv[6];
#pragma unroll
            for (int j = 0; j < 6; j++) wvv[j] = wsh[kk][tx * 6 + j];
#pragma unroll
            for (int i = 0; i < 4; i++)
#pragma unroll
                for (int j = 0; j < 6; j++) o[i][j] += av[i] * wvv[j];
        }
    }
#pragma unroll
    for (int i = 0; i < 4; i++) {
        int l = l0 + ty * 4 + i;
#pragma unroll
        for (int j = 0; j < 6; j++) {
            int n = tx * 6 + j;
            out[((size_t)(b * 96) + n) * LL + l] = o[i][j];
        }
    }
}

extern "C" void kernel_launch(void* const* d_in, const int* in_sizes, int n_in,
                              void* d_out, int out_size, void* d_ws, size_t ws_size,
                              hipStream_t stream)
{
    const float* x    = (const float*)d_in[0];
    const float* Win  = (const float*)d_in[1];
    const float* bin  = (const float*)d_in[2];
    const float* wdw  = (const float*)d_in[3];
    const float* bdw  = (const float*)d_in[4];
    const float* Alog = (const float*)d_in[5];
    const float* Dp   = (const float*)d_in[6];
    const float* Wx   = (const float*)d_in[7];
    const float* Wd   = (const float*)d_in[8];
    const float* bdl  = (const float*)d_in[9];
    const float* lng  = (const float*)d_in[10];
    const float* lnb  = (const float*)d_in[11];
    const float* Wout = (const float*)d_in[12];
    float* out = (float*)d_out;

    float* ws    = (float*)d_ws;
    __hip_bfloat16* y4 = (__hip_bfloat16*)(ws + F_Y4);
    float* xx    = ws + F_XX;    // aliases y4 slab region (dead before y4 written)
    float* zs    = ws + F_ZS;
    float* xt    = ws + F_XT;
    float* xdbl  = ws + F_XDBL;
    float* Sbuf  = ws + F_SBUF;
    float* Hbuf  = ws + F_HBUF;

    k1_inproj<<<288, 256, 0, stream>>>(x, Win, bin, xx, zs);
    k2_conv<<<1152, 192, 0, stream>>>(xx, wdw, bdw, xt);
    k3_xdbl<<<384, 192, 0, stream>>>(xt, Wx, xdbl);
    k4_pass1<<<1536, 192, 0, stream>>>(xt, xdbl, Wd, bdl, Alog, Sbuf, Hbuf);
    k4_pass2<<<96, 256, 0, stream>>>(Sbuf, Alog, Hbuf);
    k4_pass3<<<1536, 192, 0, stream>>>(xt, xdbl, Wd, bdl, Alog, Dp, Hbuf, y4);
    k5_out<<<288, 256, 0, stream>>>(y4, zs, lng, lnb, Wout, out);
}